// Round 1
// baseline (770.910 us; speedup 1.0000x reference)
//
#include <hip/hip_runtime.h>

#define B_ 64
#define C_ 512
#define T_ 16
#define HW_ 196
#define K_ 8
#define D_ 49   // 7x7 pooled positions per channel

// ---- kernel 0: zero the score accumulator (ws is poisoned 0xAA) ----
__global__ void zero_scores(float* __restrict__ score) {
    score[threadIdx.x] = 0.0f;   // launched with 1024 = B_*T_ threads
}

// ---- kernel 1: pool 14x14 -> 7x7 and accumulate partial scores ----
// One block per (b,c). score[b,t] += sum_pq pool[t][pq] * (sum_s pool[s][pq])
__global__ __launch_bounds__(256) void pool_score_kernel(const float* __restrict__ x,
                                                         float* __restrict__ score) {
    __shared__ float tile[T_ * HW_];   // 3136 floats = 12.25 KB
    __shared__ float pool[T_ * D_];    // 784
    __shared__ float ysum[D_];

    const unsigned bc = blockIdx.x;          // b*C_ + c
    const unsigned b  = bc >> 9;             // C_ = 512
    const int tid = threadIdx.x;

    // coalesced float4 load of the whole (t, hw) tile for this (b,c)
    const float4* src4 = (const float4*)(x + (size_t)bc * (T_ * HW_));
    float4* tile4 = (float4*)tile;
    for (int i = tid; i < T_ * HW_ / 4; i += 256) tile4[i] = src4[i];
    __syncthreads();

    // 2x2 average pool: pool[t][p*7+q] = mean of tile[t][2p..2p+1][2q..2q+1]
    for (int i = tid; i < T_ * D_; i += 256) {
        int t  = i / 49;
        int pq = i - t * 49;
        int p  = pq / 7;
        int q  = pq - p * 7;
        int base = t * 196 + p * 28 + q * 2;
        pool[i] = 0.25f * (tile[base] + tile[base + 1] + tile[base + 14] + tile[base + 15]);
    }
    __syncthreads();

    // per-position sum over frames
    if (tid < D_) {
        float s = 0.0f;
        for (int t = 0; t < T_; ++t) s += pool[t * 49 + tid];
        ysum[tid] = s;
    }
    __syncthreads();

    // per-frame partial score for this channel
    if (tid < T_) {
        float acc = 0.0f;
        for (int pq = 0; pq < 49; ++pq) acc += pool[tid * 49 + pq] * ysum[pq];
        atomicAdd(&score[b * T_ + tid], acc);
    }
}

// ---- kernel 2: finalize scores, rank with jax top_k tie semantics, emit sel ----
// sel[b][0..7]  = approx indices (8 largest scores), ascending
// sel[b][8..15] = detail indices (8 smallest scores), ascending
__global__ void select_kernel(const float* __restrict__ score, int* __restrict__ sel) {
    __shared__ float fs[B_ * T_];
    const int tid = threadIdx.x;         // 1024 = B_*T_
    const int b = tid >> 4;
    const int t = tid & 15;
    // scaler (1/C) and mean over keys (1/T), then prior [1,0,1,0,...]
    float v = score[tid] * (1.0f / (C_ * T_)) + ((t & 1) ? 0.0f : 1.0f);
    fs[tid] = v;
    __syncthreads();

    const float* S = fs + b * T_;
    bool memA[T_], memD[T_];
    for (int s = 0; s < T_; ++s) {
        int rd = 0, ra = 0;
        float vs = S[s];
        for (int u = 0; u < T_; ++u) {
            float vu = S[u];
            rd += (vu > vs) || (vu == vs && u < s);   // rank among largest (stable ties)
            ra += (vu < vs) || (vu == vs && u < s);   // rank among smallest (stable ties)
        }
        memA[s] = rd < K_;
        memD[s] = ra < K_;
    }
    if (memA[t]) {
        int pos = 0;
        for (int s = 0; s < t; ++s) pos += memA[s];
        sel[b * T_ + pos] = t;
    }
    if (memD[t]) {
        int pos = 0;
        for (int s = 0; s < t; ++s) pos += memD[s];
        sel[b * T_ + K_ + pos] = t;
    }
}

// ---- kernel 3: gather frames into (x_a, x_d), float4 copies ----
__global__ __launch_bounds__(256) void gather_kernel(const float* __restrict__ x,
                                                     const int* __restrict__ sel,
                                                     float* __restrict__ out) {
    const unsigned idx = blockIdx.x * 256u + threadIdx.x;  // over B_*C_*T_*49 = 25,690,112
    const unsigned q   = idx % 49u;          // float4 index within the 196-float row
    const unsigned row = idx / 49u;          // (b, c, j)
    const unsigned j   = row & 15u;
    const unsigned bc  = row >> 4;           // b*C_ + c
    const unsigned b   = bc >> 9;

    const int t = sel[b * T_ + j];
    const float4* src = (const float4*)x + (size_t)(bc * T_ + t) * (HW_ / 4) + q;

    const unsigned halfOff = (unsigned)B_ * C_ * K_ * (HW_ / 4);  // float4 units
    float4* o4 = (float4*)out;
    unsigned dst = (j < K_)
        ? ((bc * K_ + j) * (HW_ / 4) + q)
        : (halfOff + (bc * K_ + (j - K_)) * (HW_ / 4) + q);
    o4[dst] = *src;
}

extern "C" void kernel_launch(void* const* d_in, const int* in_sizes, int n_in,
                              void* d_out, int out_size, void* d_ws, size_t ws_size,
                              hipStream_t stream) {
    const float* x = (const float*)d_in[0];
    float* out = (float*)d_out;
    float* score = (float*)d_ws;                       // 1024 floats
    int*   sel   = (int*)((char*)d_ws + 4096);         // 1024 ints

    zero_scores<<<1, B_ * T_, 0, stream>>>(score);
    pool_score_kernel<<<B_ * C_, 256, 0, stream>>>(x, score);
    select_kernel<<<1, B_ * T_, 0, stream>>>(score, sel);
    // total float4s: B_*C_*T_*49 = 25,690,112 -> 100,352 blocks of 256 exactly
    gather_kernel<<<(B_ * C_ * T_ * 49) / 256, 256, 0, stream>>>(x, sel, out);
}